// Round 1
// baseline (519.736 us; speedup 1.0000x reference)
//
#include <hip/hip_runtime.h>
#include <hip/hip_bf16.h>
#include <stdint.h>

// Problem constants (from reference):
// x: [1,4,72,72,72] fp32 -> x4: [4,72,5184]
// attentions: [1,4,4608,4608] fp32
// P=9, nH=8, nW=576, L=4608, P*P=81
#define PSZ    9
#define CH     4
#define LROWS  4608   // L (also the GEMM K dim)
#define NWp    576
#define HPdim  72
#define WPdim  5184
#define NPAD   96     // 81 padded to 6 tiles of 16
#define NVALID 81
#define KSPLIT 4
#define KSEG   (LROWS / KSPLIT)   // 1152
#define KBLK   32                 // k per B chunk
#define NKB    (LROWS / KBLK)     // 144
#define BCH    (NPAD * KBLK)      // 3072 elements per (kb) B chunk

typedef short s16x8 __attribute__((ext_vector_type(8)));
typedef float f32x4 __attribute__((ext_vector_type(4)));

__device__ __forceinline__ uint16_t f2bf(float f) {
    uint32_t u = __builtin_bit_cast(uint32_t, f);
    u += 0x8000u;
    return (uint16_t)(u >> 16);
}

// Packed fp32x8 -> bf16x8 fragment (v_cvt_pk_bf16_f32, RNE)
__device__ __forceinline__ s16x8 cvt8(f32x4 a, f32x4 b) {
    union { s16x8 v; uint32_t u[4]; } r;
    __hip_bfloat162 h0 = __float22bfloat162_rn(make_float2(a.x, a.y));
    __hip_bfloat162 h1 = __float22bfloat162_rn(make_float2(a.z, a.w));
    __hip_bfloat162 h2 = __float22bfloat162_rn(make_float2(b.x, b.y));
    __hip_bfloat162 h3 = __float22bfloat162_rn(make_float2(b.z, b.w));
    __builtin_memcpy(&r.u[0], &h0, 4);
    __builtin_memcpy(&r.u[1], &h1, 4);
    __builtin_memcpy(&r.u[2], &h2, 4);
    __builtin_memcpy(&r.u[3], &h3, 4);
    return r.v;
}

__device__ __forceinline__ int count8(f32x4 a, f32x4 b) {
    return (a.x != 0.f) + (a.y != 0.f) + (a.z != 0.f) + (a.w != 0.f)
         + (b.x != 0.f) + (b.y != 0.f) + (b.z != 0.f) + (b.w != 0.f);
}

// Kernel 1: build patches bf16 in layout pb[c][kb][n(96)][ks(32)].
// pb[((c*144+kb)*96+n)*32+ks] = bf16(patches[c][n][m=kb*32+ks]),
// patches[c, n=ki*9+kj, m=bi*576+bj] = x4[c, bi*9+ki, bj*9+kj].
__global__ __launch_bounds__(256) void build_pb_kernel(
    const float* __restrict__ x, uint16_t* __restrict__ pb)
{
    __shared__ float xs[PSZ][288];
    const int blk = blockIdx.x;            // 0..575
    const int c   = blk / NKB;
    const int kb  = blk - c * NKB;
    const int bi  = kb / 18;
    const int bj0 = (kb - bi * 18) * KBLK;

    const float* src = x + (size_t)(c * HPdim + bi * PSZ) * WPdim + bj0 * PSZ;
    for (int idx = threadIdx.x; idx < PSZ * 288; idx += 256) {
        int r = idx / 288, col = idx - r * 288;
        xs[r][col] = src[(size_t)r * WPdim + col];
    }
    __syncthreads();

    uint16_t* dst = pb + (size_t)(c * NKB + kb) * BCH;
    for (int oidx = threadIdx.x; oidx < BCH; oidx += 256) {
        int n = oidx / KBLK, ks = oidx - n * KBLK;
        uint16_t v = 0;
        if (n < NVALID) {
            int ki = n / PSZ, kj = n - ki * PSZ;
            v = f2bf(xs[ki][ks * PSZ + kj]);
        }
        dst[oidx] = v;
    }
}

// Kernel 2: one block per 16(l) x 96(n) tile; 4 waves K-split (1152 each).
// v2 changes vs. previous best:
//  - attn stream loaded nontemporal (nt) so it does not evict pb/x from L2;
//    out stored nontemporal (never re-read).
//  - XCD-pinned channel mapping: blocks dispatch round-robin over the 8 XCDs
//    (blk & 7); slot>>1 selects c so each XCD touches exactly ONE channel ->
//    per-XCD L2 working set = pb[c] (884 KB) + x[c] (1.5 MB) << 4 MB.
//  - final iteration peeled: no clamped redundant reloads (~37 MB saved).
__global__ __launch_bounds__(256) void cross_gemm_kernel(
    const float* __restrict__ x,
    const float* __restrict__ attn,
    const uint16_t* __restrict__ pb,
    float* __restrict__ out)
{
    __shared__ float red[KSPLIT - 1][64][25];
    __shared__ int   cshared[KSPLIT][16];

    const int lane = threadIdx.x & 63;
    const int widx = threadIdx.x >> 6;
    const int blk  = blockIdx.x;              // 0..1151
    // XCD-pinned decomposition: 1152 = 8 slots x 144
    const int slot = blk & 7;                 // measured HW round-robin -> XCD id
    const int ii   = blk >> 3;                // 0..143
    const int c    = slot >> 1;               // one channel per XCD-pair
    const int tile = (slot & 1) * 144 + ii;   // 0..287
    const int r0   = tile * 16;
    const int li   = lane & 15;
    const int quad = lane >> 4;
    const int k0   = widx * KSEG;
    const int kb0  = k0 / KBLK;               // widx*36

    const float* ap = attn + (size_t)(c * LROWS + r0 + li) * LROWS + k0 + quad * 8;
    const uint16_t* bp = pb + (size_t)(c * NKB + kb0) * BCH + li * KBLK + quad * 8;

    f32x4 acc[6];
#pragma unroll
    for (int t = 0; t < 6; ++t) acc[t] = (f32x4){0.f, 0.f, 0.f, 0.f};

    int cnt = 0;
    const int DITERS = KSEG / 64;   // 18

    // preload set0 (k = 0)
    f32x4 a00 = __builtin_nontemporal_load((const f32x4*)(ap));
    f32x4 a01 = __builtin_nontemporal_load((const f32x4*)(ap + 4));
    s16x8 b0[6];
#pragma unroll
    for (int t = 0; t < 6; ++t) b0[t] = *(const s16x8*)(bp + t * 16 * KBLK);

    for (int dit = 0; dit < DITERS - 1; ++dit) {
        // issue set1 loads (k = 64*dit + 32) -- always in-segment
        f32x4 a10 = __builtin_nontemporal_load((const f32x4*)(ap + 32));
        f32x4 a11 = __builtin_nontemporal_load((const f32x4*)(ap + 36));
        s16x8 b1[6];
#pragma unroll
        for (int t = 0; t < 6; ++t) b1[t] = *(const s16x8*)(bp + BCH + t * 16 * KBLK);

        // compute set0
        cnt += count8(a00, a01);
        {
            s16x8 af = cvt8(a00, a01);
#pragma unroll
            for (int t = 0; t < 6; ++t)
                acc[t] = __builtin_amdgcn_mfma_f32_16x16x32_bf16(af, b0[t], acc[t], 0, 0, 0);
        }

        // advance; issue set0 loads for next trip
        ap += 64;
        bp += 2 * BCH;
        a00 = __builtin_nontemporal_load((const f32x4*)(ap));
        a01 = __builtin_nontemporal_load((const f32x4*)(ap + 4));
#pragma unroll
        for (int t = 0; t < 6; ++t) b0[t] = *(const s16x8*)(bp + t * 16 * KBLK);

        // compute set1
        cnt += count8(a10, a11);
        {
            s16x8 af = cvt8(a10, a11);
#pragma unroll
            for (int t = 0; t < 6; ++t)
                acc[t] = __builtin_amdgcn_mfma_f32_16x16x32_bf16(af, b1[t], acc[t], 0, 0, 0);
        }
    }

    // peeled final iteration (no next-trip loads)
    {
        f32x4 a10 = __builtin_nontemporal_load((const f32x4*)(ap + 32));
        f32x4 a11 = __builtin_nontemporal_load((const f32x4*)(ap + 36));
        s16x8 b1[6];
#pragma unroll
        for (int t = 0; t < 6; ++t) b1[t] = *(const s16x8*)(bp + BCH + t * 16 * KBLK);

        cnt += count8(a00, a01);
        {
            s16x8 af = cvt8(a00, a01);
#pragma unroll
            for (int t = 0; t < 6; ++t)
                acc[t] = __builtin_amdgcn_mfma_f32_16x16x32_bf16(af, b0[t], acc[t], 0, 0, 0);
        }
        cnt += count8(a10, a11);
        {
            s16x8 af = cvt8(a10, a11);
#pragma unroll
            for (int t = 0; t < 6; ++t)
                acc[t] = __builtin_amdgcn_mfma_f32_16x16x32_bf16(af, b1[t], acc[t], 0, 0, 0);
        }
    }

    // Per-wave nonzero reduction: row (r0+i) partials in lanes i, i+16, i+32, i+48
    cnt += __shfl_down(cnt, 32);
    cnt += __shfl_down(cnt, 16);
    if (lane < 16) cshared[widx][lane] = cnt;

    if (widx > 0) {
#pragma unroll
        for (int t = 0; t < 6; ++t)
#pragma unroll
            for (int r = 0; r < 4; ++r)
                red[widx - 1][lane][t * 4 + r] = acc[t][r];
    }
    __syncthreads();

    if (widx == 0) {
        // Epilogue: C/D layout col = lane&15 (n), row = quad*4 + reg (l)
#pragma unroll
        for (int reg = 0; reg < 4; ++reg) {
            const int lrow = quad * 4 + reg;
            const int cnt_r = cshared[0][lrow] + cshared[1][lrow]
                            + cshared[2][lrow] + cshared[3][lrow];
            const float scale = 1.0f / ((float)cnt_r + 1e-5f);
            const int l  = r0 + lrow;
            const int bi = l / NWp;
            const int bj = l - bi * NWp;
#pragma unroll
            for (int t = 0; t < 6; ++t) {
                const int n = t * 16 + li;
                if (n < NVALID) {
                    const float v = acc[t][reg]
                                  + red[0][lane][t * 4 + reg]
                                  + red[1][lane][t * 4 + reg]
                                  + red[2][lane][t * 4 + reg];
                    const int ki = n / PSZ, kj = n - (n / PSZ) * PSZ;
                    const size_t idx = (size_t)(c * HPdim + bi * PSZ + ki) * WPdim
                                     + (size_t)(bj * PSZ + kj);
                    const float xv = x[idx];
                    const float o  = xv * (1.0f + v * scale);
                    __builtin_nontemporal_store((o > 0.f) ? o : 0.2f * o, &out[idx]);
                }
            }
        }
    }
}

extern "C" void kernel_launch(void* const* d_in, const int* in_sizes, int n_in,
                              void* d_out, int out_size, void* d_ws, size_t ws_size,
                              hipStream_t stream)
{
    const float* x    = (const float*)d_in[0];
    const float* attn = (const float*)d_in[1];
    float* out        = (float*)d_out;
    uint16_t* pb      = (uint16_t*)d_ws;   // CH*NKB*BCH bf16 = 3.5 MB

    build_pb_kernel<<<CH * NKB, 256, 0, stream>>>(x, pb);
    cross_gemm_kernel<<<CH * 288, 256, 0, stream>>>(x, attn, pb, out);
}

// Round 2
// 502.889 us; speedup vs baseline: 1.0335x; 1.0335x over previous
//
#include <hip/hip_runtime.h>
#include <hip/hip_bf16.h>
#include <stdint.h>

// Problem constants (from reference):
// x: [1,4,72,72,72] fp32 -> x4: [4,72,5184]
// attentions: [1,4,4608,4608] fp32
// P=9, nH=8, nW=576, L=4608, P*P=81
#define PSZ    9
#define CH     4
#define LROWS  4608   // L (also the GEMM K dim)
#define NWp    576
#define HPdim  72
#define WPdim  5184
#define NPAD   96     // 81 padded to 6 tiles of 16
#define NVALID 81
#define KSPLIT 4
#define KSEG   (LROWS / KSPLIT)   // 1152
#define KBLK   32                 // k per B chunk
#define NKB    (LROWS / KBLK)     // 144
#define BCH    (NPAD * KBLK)      // 3072 elements per (kb) B chunk

typedef short s16x8 __attribute__((ext_vector_type(8)));
typedef float f32x4 __attribute__((ext_vector_type(4)));

__device__ __forceinline__ uint16_t f2bf(float f) {
    uint32_t u = __builtin_bit_cast(uint32_t, f);
    u += 0x8000u;
    return (uint16_t)(u >> 16);
}

// Packed fp32x8 -> bf16x8 fragment (v_cvt_pk_bf16_f32, RNE)
__device__ __forceinline__ s16x8 cvt8(float4 a, float4 b) {
    union { s16x8 v; uint32_t u[4]; } r;
    __hip_bfloat162 h0 = __float22bfloat162_rn(make_float2(a.x, a.y));
    __hip_bfloat162 h1 = __float22bfloat162_rn(make_float2(a.z, a.w));
    __hip_bfloat162 h2 = __float22bfloat162_rn(make_float2(b.x, b.y));
    __hip_bfloat162 h3 = __float22bfloat162_rn(make_float2(b.z, b.w));
    __builtin_memcpy(&r.u[0], &h0, 4);
    __builtin_memcpy(&r.u[1], &h1, 4);
    __builtin_memcpy(&r.u[2], &h2, 4);
    __builtin_memcpy(&r.u[3], &h3, 4);
    return r.v;
}

__device__ __forceinline__ int count8(float4 a, float4 b) {
    return (a.x != 0.f) + (a.y != 0.f) + (a.z != 0.f) + (a.w != 0.f)
         + (b.x != 0.f) + (b.y != 0.f) + (b.z != 0.f) + (b.w != 0.f);
}

// Kernel 1: build patches bf16 in layout pb[c][kb][n(96)][ks(32)].
// pb[((c*144+kb)*96+n)*32+ks] = bf16(patches[c][n][m=kb*32+ks]),
// patches[c, n=ki*9+kj, m=bi*576+bj] = x4[c, bi*9+ki, bj*9+kj].
__global__ __launch_bounds__(256) void build_pb_kernel(
    const float* __restrict__ x, uint16_t* __restrict__ pb)
{
    __shared__ float xs[PSZ][288];
    const int blk = blockIdx.x;            // 0..575
    const int c   = blk / NKB;
    const int kb  = blk - c * NKB;
    const int bi  = kb / 18;
    const int bj0 = (kb - bi * 18) * KBLK;

    const float* src = x + (size_t)(c * HPdim + bi * PSZ) * WPdim + bj0 * PSZ;
    for (int idx = threadIdx.x; idx < PSZ * 288; idx += 256) {
        int r = idx / 288, col = idx - r * 288;
        xs[r][col] = src[(size_t)r * WPdim + col];
    }
    __syncthreads();

    uint16_t* dst = pb + (size_t)(c * NKB + kb) * BCH;
    for (int oidx = threadIdx.x; oidx < BCH; oidx += 256) {
        int n = oidx / KBLK, ks = oidx - n * KBLK;
        uint16_t v = 0;
        if (n < NVALID) {
            int ki = n / PSZ, kj = n - ki * PSZ;
            v = f2bf(xs[ki][ks * PSZ + kj]);
        }
        dst[oidx] = v;
    }
}

// Kernel 2: one block per 16(l) x 96(n) tile; 4 waves K-split (1152 each).
// v3 (bisect of v2's regression):
//  - REVERTED: all nontemporal loads/stores (prime suspect: nt on the f32x4
//    attn stream scalarizes / bypasses L1 coalescing of the shared 128B lines).
//  - KEPT: XCD-pinned channel mapping (blk&7 -> XCD; one channel per XCD-pair
//    so per-XCD L2 working set = pb[c] 864KB + x[c] 1.5MB << 4MB).
//  - KEPT: peeled final iteration (no clamped redundant reloads).
__global__ __launch_bounds__(256) void cross_gemm_kernel(
    const float* __restrict__ x,
    const float* __restrict__ attn,
    const uint16_t* __restrict__ pb,
    float* __restrict__ out)
{
    __shared__ float red[KSPLIT - 1][64][25];
    __shared__ int   cshared[KSPLIT][16];

    const int lane = threadIdx.x & 63;
    const int widx = threadIdx.x >> 6;
    const int blk  = blockIdx.x;              // 0..1151
    // XCD-pinned decomposition: 1152 = 8 slots x 144
    const int slot = blk & 7;                 // measured HW round-robin -> XCD id
    const int ii   = blk >> 3;                // 0..143
    const int c    = slot >> 1;               // one channel per XCD-pair
    const int tile = (slot & 1) * 144 + ii;   // 0..287
    const int r0   = tile * 16;
    const int li   = lane & 15;
    const int quad = lane >> 4;
    const int k0   = widx * KSEG;
    const int kb0  = k0 / KBLK;               // widx*36

    const float* ap = attn + (size_t)(c * LROWS + r0 + li) * LROWS + k0 + quad * 8;
    const uint16_t* bp = pb + (size_t)(c * NKB + kb0) * BCH + li * KBLK + quad * 8;

    f32x4 acc[6];
#pragma unroll
    for (int t = 0; t < 6; ++t) acc[t] = (f32x4){0.f, 0.f, 0.f, 0.f};

    int cnt = 0;
    const int DITERS = KSEG / 64;   // 18

    // preload set0 (k = 0)
    float4 a00 = *(const float4*)(ap);
    float4 a01 = *(const float4*)(ap + 4);
    s16x8 b0[6];
#pragma unroll
    for (int t = 0; t < 6; ++t) b0[t] = *(const s16x8*)(bp + t * 16 * KBLK);

    for (int dit = 0; dit < DITERS - 1; ++dit) {
        // issue set1 loads (k = 64*dit + 32) -- always in-segment
        float4 a10 = *(const float4*)(ap + 32);
        float4 a11 = *(const float4*)(ap + 36);
        s16x8 b1[6];
#pragma unroll
        for (int t = 0; t < 6; ++t) b1[t] = *(const s16x8*)(bp + BCH + t * 16 * KBLK);

        // compute set0
        cnt += count8(a00, a01);
        {
            s16x8 af = cvt8(a00, a01);
#pragma unroll
            for (int t = 0; t < 6; ++t)
                acc[t] = __builtin_amdgcn_mfma_f32_16x16x32_bf16(af, b0[t], acc[t], 0, 0, 0);
        }

        // advance; issue set0 loads for next trip
        ap += 64;
        bp += 2 * BCH;
        a00 = *(const float4*)(ap);
        a01 = *(const float4*)(ap + 4);
#pragma unroll
        for (int t = 0; t < 6; ++t) b0[t] = *(const s16x8*)(bp + t * 16 * KBLK);

        // compute set1
        cnt += count8(a10, a11);
        {
            s16x8 af = cvt8(a10, a11);
#pragma unroll
            for (int t = 0; t < 6; ++t)
                acc[t] = __builtin_amdgcn_mfma_f32_16x16x32_bf16(af, b1[t], acc[t], 0, 0, 0);
        }
    }

    // peeled final iteration (no next-trip loads)
    {
        float4 a10 = *(const float4*)(ap + 32);
        float4 a11 = *(const float4*)(ap + 36);
        s16x8 b1[6];
#pragma unroll
        for (int t = 0; t < 6; ++t) b1[t] = *(const s16x8*)(bp + BCH + t * 16 * KBLK);

        cnt += count8(a00, a01);
        {
            s16x8 af = cvt8(a00, a01);
#pragma unroll
            for (int t = 0; t < 6; ++t)
                acc[t] = __builtin_amdgcn_mfma_f32_16x16x32_bf16(af, b0[t], acc[t], 0, 0, 0);
        }
        cnt += count8(a10, a11);
        {
            s16x8 af = cvt8(a10, a11);
#pragma unroll
            for (int t = 0; t < 6; ++t)
                acc[t] = __builtin_amdgcn_mfma_f32_16x16x32_bf16(af, b1[t], acc[t], 0, 0, 0);
        }
    }

    // Per-wave nonzero reduction: row (r0+i) partials in lanes i, i+16, i+32, i+48
    cnt += __shfl_down(cnt, 32);
    cnt += __shfl_down(cnt, 16);
    if (lane < 16) cshared[widx][lane] = cnt;

    if (widx > 0) {
#pragma unroll
        for (int t = 0; t < 6; ++t)
#pragma unroll
            for (int r = 0; r < 4; ++r)
                red[widx - 1][lane][t * 4 + r] = acc[t][r];
    }
    __syncthreads();

    if (widx == 0) {
        // Epilogue: C/D layout col = lane&15 (n), row = quad*4 + reg (l)
#pragma unroll
        for (int reg = 0; reg < 4; ++reg) {
            const int lrow = quad * 4 + reg;
            const int cnt_r = cshared[0][lrow] + cshared[1][lrow]
                            + cshared[2][lrow] + cshared[3][lrow];
            const float scale = 1.0f / ((float)cnt_r + 1e-5f);
            const int l  = r0 + lrow;
            const int bi = l / NWp;
            const int bj = l - bi * NWp;
#pragma unroll
            for (int t = 0; t < 6; ++t) {
                const int n = t * 16 + li;
                if (n < NVALID) {
                    const float v = acc[t][reg]
                                  + red[0][lane][t * 4 + reg]
                                  + red[1][lane][t * 4 + reg]
                                  + red[2][lane][t * 4 + reg];
                    const int ki = n / PSZ, kj = n - (n / PSZ) * PSZ;
                    const size_t idx = (size_t)(c * HPdim + bi * PSZ + ki) * WPdim
                                     + (size_t)(bj * PSZ + kj);
                    const float xv = x[idx];
                    const float o  = xv * (1.0f + v * scale);
                    out[idx] = (o > 0.f) ? o : 0.2f * o;
                }
            }
        }
    }
}

extern "C" void kernel_launch(void* const* d_in, const int* in_sizes, int n_in,
                              void* d_out, int out_size, void* d_ws, size_t ws_size,
                              hipStream_t stream)
{
    const float* x    = (const float*)d_in[0];
    const float* attn = (const float*)d_in[1];
    float* out        = (float*)d_out;
    uint16_t* pb      = (uint16_t*)d_ws;   // CH*NKB*BCH bf16 = 3.5 MB

    build_pb_kernel<<<CH * NKB, 256, 0, stream>>>(x, pb);
    cross_gemm_kernel<<<CH * 288, 256, 0, stream>>>(x, attn, pb, out);
}

// Round 3
// 493.370 us; speedup vs baseline: 1.0534x; 1.0193x over previous
//
#include <hip/hip_runtime.h>
#include <hip/hip_bf16.h>
#include <stdint.h>

// Problem constants (from reference):
// x: [1,4,72,72,72] fp32 -> x4: [4,72,5184]
// attentions: [1,4,4608,4608] fp32
// P=9, nH=8, nW=576, L=4608, P*P=81
#define PSZ    9
#define CH     4
#define LROWS  4608   // L (also the GEMM K dim)
#define NWp    576
#define HPdim  72
#define WPdim  5184
#define NPAD   96     // 81 padded to 6 tiles of 16
#define NVALID 81
#define KSPLIT 4
#define KSEG   (LROWS / KSPLIT)   // 1152
#define KBLK   32                 // k per B chunk
#define NKB    (LROWS / KBLK)     // 144
#define BCH    (NPAD * KBLK)      // 3072 elements per (kb) B chunk

typedef short s16x8 __attribute__((ext_vector_type(8)));
typedef float f32x4 __attribute__((ext_vector_type(4)));

__device__ __forceinline__ uint16_t f2bf(float f) {
    uint32_t u = __builtin_bit_cast(uint32_t, f);
    u += 0x8000u;
    return (uint16_t)(u >> 16);
}

// Packed fp32x8 -> bf16x8 fragment (v_cvt_pk_bf16_f32, RNE)
__device__ __forceinline__ s16x8 cvt8(float4 a, float4 b) {
    union { s16x8 v; uint32_t u[4]; } r;
    __hip_bfloat162 h0 = __float22bfloat162_rn(make_float2(a.x, a.y));
    __hip_bfloat162 h1 = __float22bfloat162_rn(make_float2(a.z, a.w));
    __hip_bfloat162 h2 = __float22bfloat162_rn(make_float2(b.x, b.y));
    __hip_bfloat162 h3 = __float22bfloat162_rn(make_float2(b.z, b.w));
    __builtin_memcpy(&r.u[0], &h0, 4);
    __builtin_memcpy(&r.u[1], &h1, 4);
    __builtin_memcpy(&r.u[2], &h2, 4);
    __builtin_memcpy(&r.u[3], &h3, 4);
    return r.v;
}

__device__ __forceinline__ int count8(float4 a, float4 b) {
    return (a.x != 0.f) + (a.y != 0.f) + (a.z != 0.f) + (a.w != 0.f)
         + (b.x != 0.f) + (b.y != 0.f) + (b.z != 0.f) + (b.w != 0.f);
}

// Kernel 1: build patches bf16 in layout pb[c][kb][n(96)][ks(32)].
// pb[((c*144+kb)*96+n)*32+ks] = bf16(patches[c][n][m=kb*32+ks]),
// patches[c, n=ki*9+kj, m=bi*576+bj] = x4[c, bi*9+ki, bj*9+kj].
__global__ __launch_bounds__(256) void build_pb_kernel(
    const float* __restrict__ x, uint16_t* __restrict__ pb)
{
    __shared__ float xs[PSZ][288];
    const int blk = blockIdx.x;            // 0..575
    const int c   = blk / NKB;
    const int kb  = blk - c * NKB;
    const int bi  = kb / 18;
    const int bj0 = (kb - bi * 18) * KBLK;

    const float* src = x + (size_t)(c * HPdim + bi * PSZ) * WPdim + bj0 * PSZ;
    for (int idx = threadIdx.x; idx < PSZ * 288; idx += 256) {
        int r = idx / 288, col = idx - r * 288;
        xs[r][col] = src[(size_t)r * WPdim + col];
    }
    __syncthreads();

    uint16_t* dst = pb + (size_t)(c * NKB + kb) * BCH;
    for (int oidx = threadIdx.x; oidx < BCH; oidx += 256) {
        int n = oidx / KBLK, ks = oidx - n * KBLK;
        uint16_t v = 0;
        if (n < NVALID) {
            int ki = n / PSZ, kj = n - ki * PSZ;
            v = f2bf(xs[ki][ks * PSZ + kj]);
        }
        dst[oidx] = v;
    }
}

// Kernel 2 (v4): one block per 32(l) x 96(n) tile; 4 waves K-split (1152 each).
// Two 16-row accumulator sets share every B fragment -> B-side L2 traffic
// halves (1.0 GB -> 0.5 GB). Grid = 576 blocks: all resident, no queue.
//  - KEPT: XCD-pinned channel mapping (blk&7 -> XCD; one channel per XCD-pair).
//  - KEPT: peeled final iteration, register ping-pong double-buffer.
__global__ __launch_bounds__(256) void cross_gemm_kernel(
    const float* __restrict__ x,
    const float* __restrict__ attn,
    const uint16_t* __restrict__ pb,
    float* __restrict__ out)
{
    __shared__ float red[KSPLIT - 1][64][51];
    __shared__ int   cshared[KSPLIT][2][16];

    const int lane = threadIdx.x & 63;
    const int widx = threadIdx.x >> 6;
    const int blk  = blockIdx.x;              // 0..575
    // XCD-pinned decomposition: 576 = 8 slots x 72
    const int slot = blk & 7;                 // measured HW round-robin -> XCD id
    const int ii   = blk >> 3;                // 0..71
    const int c    = slot >> 1;               // one channel per XCD-pair
    const int tile = (slot & 1) * 72 + ii;    // 0..143 (32-row tiles)
    const int r0   = tile * 32;
    const int li   = lane & 15;
    const int quad = lane >> 4;
    const int k0   = widx * KSEG;
    const int kb0  = k0 / KBLK;               // widx*36

    const float* ap0 = attn + (size_t)(c * LROWS + r0 + li) * LROWS + k0 + quad * 8;
    const float* ap1 = ap0 + (size_t)16 * LROWS;
    const uint16_t* bp = pb + (size_t)(c * NKB + kb0) * BCH + li * KBLK + quad * 8;

    f32x4 acc0[6], acc1[6];
#pragma unroll
    for (int t = 0; t < 6; ++t) {
        acc0[t] = (f32x4){0.f, 0.f, 0.f, 0.f};
        acc1[t] = (f32x4){0.f, 0.f, 0.f, 0.f};
    }

    int cnt0 = 0, cnt1 = 0;
    const int DITERS = KSEG / 64;   // 18

    // preload set0 (k = 0): two row-halves
    float4 a000 = *(const float4*)(ap0);
    float4 a001 = *(const float4*)(ap0 + 4);
    float4 a010 = *(const float4*)(ap1);
    float4 a011 = *(const float4*)(ap1 + 4);
    s16x8 b0[6];
#pragma unroll
    for (int t = 0; t < 6; ++t) b0[t] = *(const s16x8*)(bp + t * 16 * KBLK);

    for (int dit = 0; dit < DITERS - 1; ++dit) {
        // issue set1 loads (k = 64*dit + 32) -- always in-segment
        float4 a100 = *(const float4*)(ap0 + 32);
        float4 a101 = *(const float4*)(ap0 + 36);
        float4 a110 = *(const float4*)(ap1 + 32);
        float4 a111 = *(const float4*)(ap1 + 36);
        s16x8 b1[6];
#pragma unroll
        for (int t = 0; t < 6; ++t) b1[t] = *(const s16x8*)(bp + BCH + t * 16 * KBLK);

        // compute set0 (both halves share b0)
        cnt0 += count8(a000, a001);
        cnt1 += count8(a010, a011);
        {
            s16x8 af0 = cvt8(a000, a001);
            s16x8 af1 = cvt8(a010, a011);
#pragma unroll
            for (int t = 0; t < 6; ++t) {
                acc0[t] = __builtin_amdgcn_mfma_f32_16x16x32_bf16(af0, b0[t], acc0[t], 0, 0, 0);
                acc1[t] = __builtin_amdgcn_mfma_f32_16x16x32_bf16(af1, b0[t], acc1[t], 0, 0, 0);
            }
        }

        // advance; issue set0 loads for next trip
        ap0 += 64;
        ap1 += 64;
        bp  += 2 * BCH;
        a000 = *(const float4*)(ap0);
        a001 = *(const float4*)(ap0 + 4);
        a010 = *(const float4*)(ap1);
        a011 = *(const float4*)(ap1 + 4);
#pragma unroll
        for (int t = 0; t < 6; ++t) b0[t] = *(const s16x8*)(bp + t * 16 * KBLK);

        // compute set1
        cnt0 += count8(a100, a101);
        cnt1 += count8(a110, a111);
        {
            s16x8 af0 = cvt8(a100, a101);
            s16x8 af1 = cvt8(a110, a111);
#pragma unroll
            for (int t = 0; t < 6; ++t) {
                acc0[t] = __builtin_amdgcn_mfma_f32_16x16x32_bf16(af0, b1[t], acc0[t], 0, 0, 0);
                acc1[t] = __builtin_amdgcn_mfma_f32_16x16x32_bf16(af1, b1[t], acc1[t], 0, 0, 0);
            }
        }
    }

    // peeled final iteration (no next-trip loads)
    {
        float4 a100 = *(const float4*)(ap0 + 32);
        float4 a101 = *(const float4*)(ap0 + 36);
        float4 a110 = *(const float4*)(ap1 + 32);
        float4 a111 = *(const float4*)(ap1 + 36);
        s16x8 b1[6];
#pragma unroll
        for (int t = 0; t < 6; ++t) b1[t] = *(const s16x8*)(bp + BCH + t * 16 * KBLK);

        cnt0 += count8(a000, a001);
        cnt1 += count8(a010, a011);
        {
            s16x8 af0 = cvt8(a000, a001);
            s16x8 af1 = cvt8(a010, a011);
#pragma unroll
            for (int t = 0; t < 6; ++t) {
                acc0[t] = __builtin_amdgcn_mfma_f32_16x16x32_bf16(af0, b0[t], acc0[t], 0, 0, 0);
                acc1[t] = __builtin_amdgcn_mfma_f32_16x16x32_bf16(af1, b0[t], acc1[t], 0, 0, 0);
            }
        }
        cnt0 += count8(a100, a101);
        cnt1 += count8(a110, a111);
        {
            s16x8 af0 = cvt8(a100, a101);
            s16x8 af1 = cvt8(a110, a111);
#pragma unroll
            for (int t = 0; t < 6; ++t) {
                acc0[t] = __builtin_amdgcn_mfma_f32_16x16x32_bf16(af0, b1[t], acc0[t], 0, 0, 0);
                acc1[t] = __builtin_amdgcn_mfma_f32_16x16x32_bf16(af1, b1[t], acc1[t], 0, 0, 0);
            }
        }
    }

    // Per-wave nonzero reduction (per half): row partials in lanes i,i+16,i+32,i+48
    cnt0 += __shfl_down(cnt0, 32);
    cnt0 += __shfl_down(cnt0, 16);
    cnt1 += __shfl_down(cnt1, 32);
    cnt1 += __shfl_down(cnt1, 16);
    if (lane < 16) {
        cshared[widx][0][lane] = cnt0;
        cshared[widx][1][lane] = cnt1;
    }

    if (widx > 0) {
#pragma unroll
        for (int t = 0; t < 6; ++t)
#pragma unroll
            for (int r = 0; r < 4; ++r) {
                red[widx - 1][lane][t * 4 + r]      = acc0[t][r];
                red[widx - 1][lane][24 + t * 4 + r] = acc1[t][r];
            }
    }
    __syncthreads();

    if (widx == 0) {
        // Epilogue: C/D layout col = lane&15 (n), row = quad*4 + reg (l)
#pragma unroll
        for (int half = 0; half < 2; ++half) {
#pragma unroll
            for (int reg = 0; reg < 4; ++reg) {
                const int lrow = quad * 4 + reg;
                const int cnt_r = cshared[0][half][lrow] + cshared[1][half][lrow]
                                + cshared[2][half][lrow] + cshared[3][half][lrow];
                const float scale = 1.0f / ((float)cnt_r + 1e-5f);
                const int l  = r0 + half * 16 + lrow;
                const int bi = l / NWp;
                const int bj = l - bi * NWp;
#pragma unroll
                for (int t = 0; t < 6; ++t) {
                    const int n = t * 16 + li;
                    if (n < NVALID) {
                        const float a = half ? acc1[t][reg] : acc0[t][reg];
                        const int ro = half * 24 + t * 4 + reg;
                        const float v = a
                                      + red[0][lane][ro]
                                      + red[1][lane][ro]
                                      + red[2][lane][ro];
                        const int ki = n / PSZ, kj = n - (n / PSZ) * PSZ;
                        const size_t idx = (size_t)(c * HPdim + bi * PSZ + ki) * WPdim
                                         + (size_t)(bj * PSZ + kj);
                        const float xv = x[idx];
                        const float o  = xv * (1.0f + v * scale);
                        out[idx] = (o > 0.f) ? o : 0.2f * o;
                    }
                }
            }
        }
    }
}

extern "C" void kernel_launch(void* const* d_in, const int* in_sizes, int n_in,
                              void* d_out, int out_size, void* d_ws, size_t ws_size,
                              hipStream_t stream)
{
    const float* x    = (const float*)d_in[0];
    const float* attn = (const float*)d_in[1];
    float* out        = (float*)d_out;
    uint16_t* pb      = (uint16_t*)d_ws;   // CH*NKB*BCH bf16 = 3.5 MB

    build_pb_kernel<<<CH * NKB, 256, 0, stream>>>(x, pb);
    cross_gemm_kernel<<<CH * 144, 256, 0, stream>>>(x, attn, pb, out);
}